// Round 9
// baseline (451.102 us; speedup 1.0000x reference)
//
#include <hip/hip_runtime.h>
#include <math.h>

#define N_EDGES 4096
#define NN1 256
#define NN2 128

// ---------------- reduction helpers ----------------
template<int NT>
__device__ inline float block_sum(float v, float* red, int t){
  red[t] = v; __syncthreads();
  #pragma unroll
  for (int st = NT/2; st > 0; st >>= 1){
    if (t < st) red[t] += red[t+st];
    __syncthreads();
  }
  float r = red[0]; __syncthreads();
  return r;
}
template<int NT>
__device__ inline float block_max(float v, float* red, int t){
  red[t] = v; __syncthreads();
  #pragma unroll
  for (int st = NT/2; st > 0; st >>= 1){
    if (t < st) red[t] = fmaxf(red[t], red[t+st]);
    __syncthreads();
  }
  float r = red[0]; __syncthreads();
  return r;
}
template<int NT>
__device__ inline int block_min_int(int v, int* red, int t){
  red[t] = v; __syncthreads();
  #pragma unroll
  for (int st = NT/2; st > 0; st >>= 1){
    if (t < st) red[t] = min(red[t], red[t+st]);
    __syncthreads();
  }
  int r = red[0]; __syncthreads();
  return r;
}

// ---------------- conv3x3(SAME): 16x32 tile, 4x2 pts/thread, CPT=4 ----------------
// Block 256 thr = 4 waves. Tile = 16 (x) x 32 (y) conv points. Thread (qx,qy):
// points x: 2qx..2qx+1, y: 4qy..4qy+3 (8 points) for 4 couts (wave wv owns
// couts cg*16 + wv*4 + 0..3). Patch 6x4 -> 12 ds_read_b64; weights packed
// [c][k][co16] -> 9 broadcast b128 per channel. 288 FMA / 21 LDS instr.
// Input pre-padded [CIN][H+2][in_row], zero border.
// Register-prefetch pipeline (hoisted descriptors, dbuf, 1 barrier/chunk).
// SPLITK==1: fused bias+relu+pool2x2 -> padded interior out.
// SPLITK>1 : raw conv partials [split][COUT][H][W].
template<int CIN, int COUT, int CHUNK, int SPLITK>
__global__ __launch_bounds__(256) void conv9(
    const float* __restrict__ in, const float* __restrict__ w,
    const float* __restrict__ bias, float* __restrict__ out,
    int H, int W, int in_row, int in_ch, int out_row, int out_ch)
{
  constexpr int CPB  = CIN / SPLITK;
  constexpr int NCH  = CPB / CHUNK;
  constexpr int CGRPS = COUT / 16;
  constexpr int TROW = 20;                 // 16+halo staged as 5 float4
  constexpr int TSZ  = CHUNK * 34 * TROW;
  constexpr int WSZ  = CHUNK * 9 * 16;
  constexpr int TJ   = CHUNK * 34 * 5;     // float4 tile jobs
  constexpr int WN   = CHUNK * 9 * 16;     // weight scalar jobs
  constexpr int NST  = (TJ + 255) / 256;
  constexpr int NSW  = (WN + 255) / 256;
  __shared__ float tile[2][TSZ];
  __shared__ float wlds[2][WSZ];

  const int cg = blockIdx.x % CGRPS;
  const int bx = blockIdx.x / CGRPS;
  const int by = blockIdx.y;
  const int split = blockIdx.z;
  const int tid = threadIdx.x;
  const int lane = tid & 63;
  const int wv = tid >> 6;
  const int qx = lane & 7, qy = lane >> 3;
  const int c_base = split * CPB;

  // hoisted staging descriptors (chunk-invariant); -1 = inactive slot
  int tsrc[NST], tlds[NST];
  #pragma unroll
  for (int s2 = 0; s2 < NST; ++s2){
    int j = tid + s2*256;
    if (j < TJ){
      int row = j / 5, part = j - row*5;
      int c = row / 34, rr = row - c*34;
      tsrc[s2] = (c_base + c)*in_ch + (32*by + rr)*in_row + 16*bx + 4*part;
      tlds[s2] = (c*34 + rr)*TROW + 4*part;
    } else { tsrc[s2] = -1; tlds[s2] = 0; }
  }
  int wsrc[NSW], wldo[NSW];
  #pragma unroll
  for (int s2 = 0; s2 < NSW; ++s2){
    int e = tid + s2*256;
    if (e < WN){
      int co = e / (CHUNK*9);
      int rem = e - co*CHUNK*9;
      int c = rem / 9, k = rem - c*9;
      wsrc[s2] = ((cg*16 + co)*CIN + c_base + c)*9 + k;   // k fastest: coalesced
      wldo[s2] = (c*9 + k)*16 + co;                       // [c][k][co] packed
    } else { wsrc[s2] = -1; wldo[s2] = 0; }
  }

  float acc[4][8];
  #pragma unroll
  for (int co = 0; co < 4; ++co)
    #pragma unroll
    for (int i = 0; i < 8; ++i) acc[co][i] = 0.f;

  float4 rt[NST];
  float  rw[NSW];

  auto LD = [&](int c0){
    #pragma unroll
    for (int s2 = 0; s2 < NST; ++s2)
      if (tsrc[s2] >= 0) rt[s2] = *(const float4*)&in[tsrc[s2] + c0*in_ch];
    #pragma unroll
    for (int s2 = 0; s2 < NSW; ++s2)
      if (wsrc[s2] >= 0) rw[s2] = w[wsrc[s2] + c0*9];
  };
  auto ST = [&](int b){
    #pragma unroll
    for (int s2 = 0; s2 < NST; ++s2)
      if (tsrc[s2] >= 0) *(float4*)&tile[b][tlds[s2]] = rt[s2];
    #pragma unroll
    for (int s2 = 0; s2 < NSW; ++s2)
      if (wsrc[s2] >= 0) wlds[b][wldo[s2]] = rw[s2];
  };
  auto COMPUTE = [&](int b){
    #pragma unroll
    for (int c = 0; c < CHUNK; ++c){
      float p[6][4];
      const int tb = (c*34 + 4*qy)*TROW + 2*qx;
      #pragma unroll
      for (int i = 0; i < 6; ++i){
        float2 lo = *(const float2*)&tile[b][tb + i*TROW];
        float2 hi = *(const float2*)&tile[b][tb + i*TROW + 2];
        p[i][0]=lo.x; p[i][1]=lo.y; p[i][2]=hi.x; p[i][3]=hi.y;
      }
      #pragma unroll
      for (int k = 0; k < 9; ++k){
        const int ky = k / 3, kx = k - ky*3;
        float4 wk = *(const float4*)&wlds[b][(c*9 + k)*16 + wv*4];  // broadcast
        float wa[4] = {wk.x, wk.y, wk.z, wk.w};
        #pragma unroll
        for (int co = 0; co < 4; ++co)
          #pragma unroll
          for (int dy = 0; dy < 4; ++dy)
            #pragma unroll
            for (int dx = 0; dx < 2; ++dx)
              acc[co][dy*2+dx] += wa[co] * p[dy+ky][dx+kx];
      }
    }
  };

  LD(0); ST(0); __syncthreads();
  for (int ch = 0; ch < NCH; ++ch){
    if (ch + 1 < NCH) LD((ch+1)*CHUNK);   // next-chunk loads in flight
    COMPUTE(ch & 1);
    if (ch + 1 < NCH){
      ST((ch+1) & 1);                     // other buffer: safe before barrier
      __syncthreads();
    }
  }

  if (SPLITK == 1){
    #pragma unroll
    for (int co = 0; co < 4; ++co){
      int cout = cg*16 + wv*4 + co;
      float bsv = bias[cout];
      #pragma unroll
      for (int yy = 0; yy < 2; ++yy){
        float m = fmaxf(fmaxf(acc[co][4*yy+0], acc[co][4*yy+1]),
                        fmaxf(acc[co][4*yy+2], acc[co][4*yy+3])) + bsv;
        int oy = 16*by + 2*qy + yy, ox = 8*bx + qx;
        out[cout*out_ch + oy*out_row + ox] = fmaxf(m, 0.f);
      }
    }
  } else {
    #pragma unroll
    for (int co = 0; co < 4; ++co){
      int cout = cg*16 + wv*4 + co;
      float* pb = out + (split*COUT + cout)*H*W;
      #pragma unroll
      for (int dy = 0; dy < 4; ++dy){
        int y = 32*by + 4*qy + dy, x0 = 16*bx + 2*qx;
        *(float2*)&pb[y*W + x0] = make_float2(acc[co][dy*2], acc[co][dy*2+1]);
      }
    }
  }
}

// sum fp32 partials over splits, then bias + relu + maxpool2x2 -> pitched out
template<int SPLITK>
__global__ __launch_bounds__(256) void reduce_pool(
    const float* __restrict__ pbuf, const float* __restrict__ bias,
    float* __restrict__ out, int COUT, int H, int W, int out_row, int out_ch)
{
  int idx = blockIdx.x*256 + threadIdx.x;
  const int OW = W >> 1, OH = H >> 1;
  if (idx >= COUT*OH*OW) return;
  int px = idx % OW; int t = idx / OW; int py = t % OH; int cout = t / OH;
  unsigned base = (unsigned)cout*H*W + (unsigned)(2*py)*W + 2*px;
  unsigned sstr = (unsigned)COUT*H*W;
  float s00=0.f, s01=0.f, s10=0.f, s11=0.f;
  #pragma unroll
  for (int s=0;s<SPLITK;s++){
    const float* pb = pbuf + s*sstr + base;
    s00 += pb[0]; s01 += pb[1]; s10 += pb[W]; s11 += pb[W+1];
  }
  float m = fmaxf(fmaxf(s00,s01),fmaxf(s10,s11)) + bias[cout];
  out[cout*out_ch + py*out_row + px] = fmaxf(m, 0.f);
}

// ---------------- graph kernels ----------------
__global__ void build_adj_kernel(const int* __restrict__ ei, float* adj, float* cnt){
  int e = blockIdx.x*256 + threadIdx.x;
  if (e < N_EDGES){
    int s = ei[e], d = ei[N_EDGES + e];
    atomicAdd(&adj[s*NN1 + d], 1.0f);   // integer-valued -> order independent
    atomicAdd(&cnt[d], 1.0f);
  }
}

// transpose the 4 sage weight matrices [128][256] -> [256][128], packed
__global__ void transpose4_kernel(const float* __restrict__ a, const float* __restrict__ b,
    const float* __restrict__ c, const float* __restrict__ d, float* __restrict__ o){
  int m = blockIdx.y, k = blockIdx.x, cc = threadIdx.x;  // 128 thr
  const float* src = (m==0)?a:(m==1)?b:(m==2)?c:d;
  o[(size_t)m*32768 + k*128 + cc] = src[cc*256 + k];
}

__global__ __launch_bounds__(256) void agg_kernel(const float* __restrict__ adj,
    const float* __restrict__ cnt, const float* __restrict__ org, float* __restrict__ aggn){
  int d = blockIdx.x, j = threadIdx.x;
  float acc = 0.f;
  for (int s = 0; s < NN1; ++s){
    float a = adj[s*NN1 + d];
    if (a != 0.f) acc += a * org[s*NN1 + j];
  }
  aggn[d*NN1 + j] = acc / fmaxf(cnt[d], 1.0f);
}

// transposed-weight sage12: coalesced weight reads; also writes s^T
__global__ __launch_bounds__(128) void sage12_kernel(
    const float* __restrict__ aggn, const float* __restrict__ org,
    const float* __restrict__ wl1t, const float* __restrict__ bl1, const float* __restrict__ wr1t,
    const float* __restrict__ wl2t, const float* __restrict__ bl2, const float* __restrict__ wr2t,
    float* __restrict__ x1, float* __restrict__ s_out, float* __restrict__ st,
    float* __restrict__ entpart)
{
  __shared__ float sa[NN1], so[NN1], red[128];
  int n = blockIdx.x, c = threadIdx.x;
  for (int k = c; k < NN1; k += 128){ sa[k] = aggn[n*NN1+k]; so[k] = org[n*NN1+k]; }
  __syncthreads();
  float p1 = bl1[c], p2 = bl2[c];
  for (int k = 0; k < NN1; ++k){
    float av = sa[k], ov = so[k];
    p1 += av*wl1t[k*128+c] + ov*wr1t[k*128+c];
    p2 += av*wl2t[k*128+c] + ov*wr2t[k*128+c];
  }
  float n1s = block_sum<128>(p1*p1, red, c);
  x1[n*128 + c] = p1 / fmaxf(sqrtf(n1s), 1e-12f);
  float n2s = block_sum<128>(p2*p2, red, c);
  float p2n = p2 / fmaxf(sqrtf(n2s), 1e-12f);
  float mx = block_max<128>(p2n, red, c);
  float ev = expf(p2n - mx);
  float ssum = block_sum<128>(ev, red, c);
  float sv = ev / ssum;
  s_out[n*128 + c] = sv;
  st[c*NN1 + n] = sv;
  float esum = block_sum<128>(-sv * logf(sv + 1e-15f), red, c);
  if (c == 0) entpart[n] = esum;
}

__global__ __launch_bounds__(128) void xp_kernel(const float* __restrict__ s,
    const float* __restrict__ x1, float* __restrict__ xp){
  int cc = blockIdx.x, f = threadIdx.x;
  float acc = 0.f;
  for (int n = 0; n < NN1; ++n) acc += s[n*128+cc] * x1[n*128+f];
  xp[cc*128+f] = acc;
}

__global__ __launch_bounds__(128) void adj_s_kernel(const float* __restrict__ adj,
    const float* __restrict__ s, float* __restrict__ t){
  int n = blockIdx.x, c = threadIdx.x;
  float acc = 0.f;
  for (int m = 0; m < NN1; ++m){
    float a = adj[n*NN1+m];
    if (a != 0.f) acc += a * s[m*128+c];
  }
  t[n*128+c] = acc;
}

__global__ __launch_bounds__(128) void adjp_kernel(const float* __restrict__ s,
    const float* __restrict__ t, float* __restrict__ adjp){
  int cc = blockIdx.x, d = threadIdx.x;
  float acc = 0.f;
  for (int n = 0; n < NN1; ++n) acc += s[n*128+cc] * t[n*128+d];
  adjp[cc*128+d] = acc;
}

// per-row n: sum_m (adj[n][m] - s[n]·s[m])^2 ; uses s^T for coalesced reads
__global__ __launch_bounds__(256) void link_kernel(const float* __restrict__ adj,
    const float* __restrict__ s, const float* __restrict__ st, float* __restrict__ linkpart){
  __shared__ float sn[128]; __shared__ float red[256];
  int n = blockIdx.x, m = threadIdx.x;
  if (m < 128) sn[m] = s[n*128+m];
  __syncthreads();
  float dot = 0.f;
  for (int c = 0; c < 128; ++c) dot += sn[c]*st[c*NN1 + m];
  float v = adj[n*NN1+m] - dot;
  float part = block_sum<256>(v*v, red, m);
  if (m == 0) linkpart[n] = part;
}

__global__ __launch_bounds__(128) void binarize_kernel(const float* __restrict__ adjp,
    float* __restrict__ edge_out, float* __restrict__ ei2_out, int* __restrict__ cols){
  __shared__ float red[128]; __shared__ int redi[128];
  int i = blockIdx.x, j = threadIdx.x;
  float v = adjp[i*128+j];
  float mx = block_max<128>(v, red, j);
  edge_out[i*128+j] = (v == mx) ? 1.0f : 0.0f;
  int cand = (v == mx) ? j : (1 << 30);
  int cmin = block_min_int<128>(cand, redi, j);
  if (j == 0){
    cols[i] = cmin;
    ei2_out[i] = (float)i;
    ei2_out[128 + i] = (float)cmin;
  }
}

__global__ __launch_bounds__(128) void sage3_agg_kernel(const float* __restrict__ xp,
    const int* __restrict__ cols, float* __restrict__ aggn3){
  int d = blockIdx.x, f = threadIdx.x;
  float acc = 0.f, c = 0.f;
  for (int i = 0; i < NN2; ++i){
    if (cols[i] == d){ acc += xp[i*128+f]; c += 1.f; }
  }
  aggn3[d*128+f] = acc / fmaxf(c, 1.f);
}

__global__ __launch_bounds__(128) void sage3_out_kernel(const float* __restrict__ aggn3,
    const float* __restrict__ xp,
    const float* __restrict__ wl3, const float* __restrict__ bl3, const float* __restrict__ wr3,
    float* __restrict__ nodes_out)
{
  __shared__ float red[128];
  int n = blockIdx.x, k = threadIdx.x;
  float ag = aggn3[n*128+k];
  float xv = xp[n*128+k];
  float q0 = block_sum<128>(ag*wl3[k]     + xv*wr3[k],     red, k);
  float q1 = block_sum<128>(ag*wl3[128+k] + xv*wr3[128+k], red, k);
  if (k == 0){
    float p0 = q0 + bl3[0], p1 = q1 + bl3[1];
    float nm = fmaxf(sqrtf(p0*p0 + p1*p1), 1e-12f);
    nodes_out[n*2+0] = tanhf(p0/nm);
    nodes_out[n*2+1] = tanhf(p1/nm);
  }
}

__global__ __launch_bounds__(256) void finalize_kernel(const float* __restrict__ linkpart,
    const float* __restrict__ entpart, float* __restrict__ d_out)
{
  __shared__ float red[256];
  int t = threadIdx.x;
  float ls = block_sum<256>(linkpart[t], red, t);
  float es = block_sum<256>(entpart[t], red, t);
  float v0 = 0.f, v1 = 0.f;
  if (t < 128){ v0 = d_out[4 + t*2 + 0]; v1 = d_out[4 + t*2 + 1]; }
  float s0 = block_sum<256>(v0, red, t);
  float s1 = block_sum<256>(v1, red, t);
  if (t == 0){
    d_out[0] = s0;
    d_out[1] = s1;
    d_out[2] = sqrtf(ls)/65536.0f + sqrtf(16256.0f)/16384.0f;  // ll1 + ll2(const)
    d_out[3] = es/256.0f;                                      // el1 + el2(=0)
  }
}

// copy raw 5x512x512 input into zero-bordered P0 [5][514][516]
__global__ __launch_bounds__(256) void pad_copy(const float* __restrict__ src,
                                                float* __restrict__ dst){
  int idx = blockIdx.x*256 + threadIdx.x;   // 5*512*128 float4 jobs
  if (idx >= 5*512*128) return;
  int c = idx >> 16;
  int rem = idx & 65535;
  int y = rem >> 7, xq = rem & 127;
  float4 v = *(const float4*)&src[c*262144 + y*512 + 4*xq];
  float* d = &dst[c*(514*516) + (y+1)*516 + 1 + 4*xq];
  d[0]=v.x; d[1]=v.y; d[2]=v.z; d[3]=v.w;
}

extern "C" void kernel_launch(void* const* d_in, const int* in_sizes, int n_in,
                              void* d_out_v, int out_size, void* d_ws, size_t ws_size,
                              hipStream_t stream)
{
  (void)in_sizes; (void)n_in; (void)out_size; (void)ws_size;
  const float* input = (const float*)d_in[0];
  const int*   ei    = (const int*)  d_in[1];
  const float* w1 = (const float*)d_in[2];  const float* b1 = (const float*)d_in[3];
  const float* w2 = (const float*)d_in[4];  const float* b2 = (const float*)d_in[5];
  const float* w3 = (const float*)d_in[6];  const float* b3 = (const float*)d_in[7];
  const float* w4 = (const float*)d_in[8];  const float* b4 = (const float*)d_in[9];
  const float* w5 = (const float*)d_in[10]; const float* b5 = (const float*)d_in[11];
  const float* s1wl = (const float*)d_in[12]; const float* s1bl = (const float*)d_in[13];
  const float* s1wr = (const float*)d_in[14];
  const float* s2wl = (const float*)d_in[15]; const float* s2bl = (const float*)d_in[16];
  const float* s2wr = (const float*)d_in[17];
  const float* s3wl = (const float*)d_in[18]; const float* s3bl = (const float*)d_in[19];
  const float* s3wr = (const float*)d_in[20];
  float* d_out = (float*)d_out_v;
  float* ws = (float*)d_ws;

  // Padded buffers [C][H+2][row], row = W+2 padded to x4; interior at +row+1.
  // P1: 32x258x260  P2: 64x130x132  P3: 128x66x68  P4: 256x34x36
  float* P1  = ws;                    // 2,146,560
  float* P2  = ws + 2146560;          // 1,098,240 (graph scratch aliases after L3)
  float* P3  = ws + 3244800;          //   574,464
  float* P4  = ws + 3819264;          //   313,344
  float* org = ws + 4132608;          //    65,536
  float* P0  = ws + 4198144;          // 1,326,120  (total 5,524,264 floats = 22.1 MB)
  float* PART = P1;                   // split-K partials (<=2,097,152; P1 dead after L2)

  // graph scratch (after convs) aliases P2 region
  float* G        = P2;
  float* adj1     = G;                   // 65,536
  float* cnt      = G + 65536;           // 256
  float* aggn3    = G + 65792;           // 16,384
  float* aggn     = G + 82176;           // 65,536
  float* x1       = G + 147712;          // 32,768
  float* s        = G + 180480;          // 32,768
  float* t        = G + 213248;          // 32,768
  float* xp       = G + 246016;          // 16,384
  float* adjp     = G + 262400;          // 16,384
  int*   cols     = (int*)(G + 278784);  // 128
  float* linkpart = G + 278912;          // 256
  float* entpart  = G + 279168;          // 256
  float* wt       = G + 279424;          // 4 x 32,768 transposed sage weights
  float* st       = G + 410496;          // 32,768 (s^T)

  const int p1r = 260, p1c = 258*260;
  const int p2r = 132, p2c = 130*132;
  const int p3r = 68,  p3c = 66*68;
  const int p4r = 36,  p4c = 34*36;
  const int p0r = 516, p0c = 514*516;

  // zero all padded buffers incl. P0 (borders must be 0; interiors overwritten)
  hipMemsetAsync(ws, 0, (size_t)5524264*sizeof(float), stream);
  pad_copy<<<dim3(1280), 256, 0, stream>>>(input, P0);

  // L1: 5->32 @512   (CGRPS=2,  grid 64x16 = 1024 blocks, CHUNK=5, NCH=1)
  conv9<5,32,5,1>    <<<dim3(64,16,1), 256, 0, stream>>>(P0, w1, b1, P1+p1r+1, 512,512, p0r,p0c, p1r,p1c);
  // L2: 32->64 @256  (CGRPS=4,  grid 64x8  = 512 blocks)
  conv9<32,64,4,1>   <<<dim3(64,8,1),  256, 0, stream>>>(P1, w2, b2, P2+p2r+1, 256,256, p1r,p1c, p2r,p2c);
  // L3: 64->128 @128 (CGRPS=8,  grid 64x4  = 256 blocks)
  conv9<64,128,4,1>  <<<dim3(64,4,1),  256, 0, stream>>>(P2, w3, b3, P3+p3r+1, 128,128, p2r,p2c, p3r,p3c);
  // L4: 128->256 @64, splitK2 -> PART (2x256x64x64), reduce -> P4 interior
  conv9<128,256,4,2> <<<dim3(64,2,2),  256, 0, stream>>>(P3, w4, b4, PART, 64,64, p3r,p3c, 0,0);
  reduce_pool<2>     <<<dim3(1024),    256, 0, stream>>>(PART, b4, P4+p4r+1, 256, 64,64, p4r,p4c);
  // L5: 256->256 @32, splitK8 -> PART (8x256x32x32), reduce -> org (unpadded)
  conv9<256,256,4,8> <<<dim3(32,1,8),  256, 0, stream>>>(P4, w5, b5, PART, 32,32, p4r,p4c, 0,0);
  reduce_pool<8>     <<<dim3(256),     256, 0, stream>>>(PART, b5, org, 256, 32,32, 16,256);

  // graph tail
  hipMemsetAsync(adj1, 0, (65536 + 256)*sizeof(float), stream);
  transpose4_kernel<<<dim3(256,4), 128, 0, stream>>>(s1wl, s1wr, s2wl, s2wr, wt);
  build_adj_kernel<<<dim3(16),  256, 0, stream>>>(ei, adj1, cnt);
  agg_kernel      <<<dim3(256), 256, 0, stream>>>(adj1, cnt, org, aggn);
  sage12_kernel   <<<dim3(256), 128, 0, stream>>>(aggn, org, wt, s1bl, wt+32768,
                                                  wt+65536, s2bl, wt+98304, x1, s, st, entpart);
  xp_kernel       <<<dim3(128), 128, 0, stream>>>(s, x1, xp);
  adj_s_kernel    <<<dim3(256), 128, 0, stream>>>(adj1, s, t);
  adjp_kernel     <<<dim3(128), 128, 0, stream>>>(s, t, adjp);
  link_kernel     <<<dim3(256), 256, 0, stream>>>(adj1, s, st, linkpart);
  binarize_kernel <<<dim3(128), 128, 0, stream>>>(adjp, d_out + 260, d_out + 16644, cols);
  sage3_agg_kernel<<<dim3(128), 128, 0, stream>>>(xp, cols, aggn3);
  sage3_out_kernel<<<dim3(128), 128, 0, stream>>>(aggn3, xp, s3wl, s3bl, s3wr, d_out + 4);
  finalize_kernel <<<dim3(1),   256, 0, stream>>>(linkpart, entpart, d_out);
}